// Round 2
// baseline (420.987 us; speedup 1.0000x reference)
//
#include <hip/hip_runtime.h>
#include <hip/hip_bf16.h>
#include <hip/hip_fp16.h>
#include <type_traits>

// ---------------------------------------------------------------------------
// GCN: out = relu(Agg(x@W1)+b1) -> relu(Agg(.@W2)+b2) -> .@Wc+bc
// Agg(h)[i] = dinv[i]^2*h[i] + sum_{e: dst=i} dinv[i]*dinv[src]*h[src]
// R1-R6: see history. R7: agg 4x16 groups, dwordx4 gathers, bpermute bcast.
// R8: (a) GEMM rewritten as gemm_bres: whole Wt resident in LDS (loaded
//     once, +8-half pad = uniform banks, 16B aligned), ZERO barriers in
//     k-loop, A fragments loaded global->reg directly (fp32 cvt in-reg),
//     MT=2 row-tiles/wave, full k-unroll -> pure ILP latency hiding.
//     Old gemm: MfmaUtil 3.5%, VALU 6%, HBM 14%, 3M bank conflicts, 67us.
//     (b) agg inner loop: explicit 16-edge batches (8 bpermute + 4
//     independent dwordx4 in flight) -- unroll-2 was leaving ~1.5 loads
//     outstanding (25 cyc/edge = latency-bound at HBM 43%).
// ---------------------------------------------------------------------------

typedef _Float16 half8 __attribute__((ext_vector_type(8)));
typedef _Float16 half4v __attribute__((ext_vector_type(4)));
typedef float floatx4 __attribute__((ext_vector_type(4)));

#define EPB 8192   // edges per block in histA/scatterA

// ------------------------- scan helpers (unchanged) ------------------------

__device__ inline int block_incl_scan_256(int t, int* tmp) {
    int tid = threadIdx.x;
    tmp[tid] = t;
    __syncthreads();
    #pragma unroll
    for (int off = 1; off < 256; off <<= 1) {
        int v = (tid >= off) ? tmp[tid - off] : 0;
        __syncthreads();
        tmp[tid] += v;
        __syncthreads();
    }
    return tmp[tid];
}

template <int ITEMS>
__global__ __launch_bounds__(256) void k_scan1(const int* __restrict__ v,
                                               int* __restrict__ bsum, int n) {
    __shared__ int tmp[256];
    int base = blockIdx.x * (256 * ITEMS) + threadIdx.x * ITEMS;
    int t = 0;
    #pragma unroll
    for (int l = 0; l < ITEMS; ++l) {
        int i = base + l;
        t += (i < n) ? v[i] : 0;
    }
    block_incl_scan_256(t, tmp);
    if (threadIdx.x == 0) bsum[blockIdx.x] = tmp[255];
}

__global__ __launch_bounds__(256) void k_scan2(int* __restrict__ bsum, int nb) {
    __shared__ int tmp[256];
    int tid = threadIdx.x;
    int v = (tid < nb) ? bsum[tid] : 0;
    block_incl_scan_256(v, tmp);
    if (tid < nb) bsum[tid] = tid ? tmp[tid - 1] : 0;
}

template <int ITEMS>
__global__ __launch_bounds__(256) void k_scan3(const int* __restrict__ vin,
                                               const int* __restrict__ bsum,
                                               int* __restrict__ rp, int n) {
    __shared__ int tmp[256];
    int base = blockIdx.x * (256 * ITEMS) + threadIdx.x * ITEMS;
    int v[ITEMS];
    int t = 0;
    #pragma unroll
    for (int l = 0; l < ITEMS; ++l) {
        int i = base + l;
        v[l] = (i < n) ? vin[i] : 0;
        t += v[l];
    }
    block_incl_scan_256(t, tmp);
    int run = bsum[blockIdx.x] + (threadIdx.x ? tmp[threadIdx.x - 1] : 0);
    #pragma unroll
    for (int l = 0; l < ITEMS; ++l) {
        int i = base + l;
        if (i < n) rp[i] = run;
        run += v[l];
    }
}

// ----------------------- bucket-sort CSR build -----------------------------

__global__ __launch_bounds__(256) void k_histA(const int* __restrict__ dst,
                                               int* __restrict__ histM,
                                               int E, int nblk) {
    __shared__ int h[512];
    int tid = threadIdx.x;
    for (int i = tid; i < 512; i += 256) h[i] = 0;
    __syncthreads();
    int base = blockIdx.x * EPB;
    #pragma unroll 4
    for (int l = 0; l < EPB / 256; ++l) {
        int i = base + l * 256 + tid;
        if (i < E) atomicAdd(&h[dst[i] >> 8], 1);
    }
    __syncthreads();
    for (int i = tid; i < 512; i += 256)
        histM[i * nblk + blockIdx.x] = h[i];
}

__global__ __launch_bounds__(256) void k_scatterA(const int* __restrict__ src,
                                                  const int* __restrict__ dst,
                                                  const int* __restrict__ histS,
                                                  unsigned long long* __restrict__ eB,
                                                  int E, int nblk) {
    __shared__ int bse[512];
    __shared__ int cnt[512];
    int tid = threadIdx.x;
    for (int i = tid; i < 512; i += 256) {
        bse[i] = histS[i * nblk + blockIdx.x];
        cnt[i] = 0;
    }
    __syncthreads();
    int base = blockIdx.x * EPB;
    #pragma unroll 4
    for (int l = 0; l < EPB / 256; ++l) {
        int i = base + l * 256 + tid;
        if (i < E) {
            int d = dst[i];
            int s = src[i];
            int b = d >> 8;
            int r = atomicAdd(&cnt[b], 1);
            eB[bse[b] + r] = ((unsigned long long)(unsigned)d << 32) | (unsigned)s;
        }
    }
}

#define BCAP 4608   // bucket capacity: mean 4096, sigma~64 -> 8 sigma head
__global__ __launch_bounds__(256) void k_sortB(const unsigned long long* __restrict__ eB,
                                               const int* __restrict__ histS,
                                               int* __restrict__ srcS,
                                               int* __restrict__ rowptr,
                                               float* __restrict__ dinv,
                                               int n, int E, int nblk) {
    const int b   = blockIdx.x;
    const int tid = threadIdx.x;
    const int ni0 = b << 8;
    int s0 = histS[b * nblk];
    int s1 = (b < 511) ? histS[(b + 1) * nblk] : E;
    int cnt = s1 - s0;
    if (cnt > BCAP) cnt = BCAP;          // statistically unreachable
    if (cnt == 0 && ni0 > n) return;

    __shared__ int hist[256];
    __shared__ int tmp[256];
    __shared__ int baseA[256];
    __shared__ int cntA[256];
    __shared__ int dstL[BCAP];
    __shared__ unsigned srcL[BCAP];
    __shared__ int lbA[256];

    hist[tid] = 0;
    cntA[tid] = 0;
    __syncthreads();
    for (int i = s0 + tid; i < s0 + cnt; i += 256) {
        int d = (int)(eB[i] >> 32);
        atomicAdd(&hist[d & 255], 1);
    }
    __syncthreads();
    int own  = hist[tid];
    int incl = block_incl_scan_256(own, tmp);
    baseA[tid] = incl - own;
    __syncthreads();
    for (int i = s0 + tid; i < s0 + cnt; i += 256) {
        unsigned long long v = eB[i];
        int d = (int)(v >> 32);
        int dig = d & 255;
        int r = atomicAdd(&cntA[dig], 1);
        int pos = baseA[dig] + r;
        dstL[pos] = d;
        srcL[pos] = (unsigned)v;
    }
    __syncthreads();
    for (int j = tid; j < cnt; j += 256)
        srcS[s0 + j] = (int)srcL[j];
    if (ni0 <= n) {
        int i = ni0 + tid;
        int lo = 0, hi = cnt;
        while (lo < hi) {
            int mid = (lo + hi) >> 1;
            if (dstL[mid] < i) lo = mid + 1; else hi = mid;
        }
        lbA[tid] = lo;
        __syncthreads();
        if (i <= n) {
            rowptr[i] = s0 + lo;
            if (i < n) {
                int ub = (tid < 255) ? lbA[tid + 1] : cnt;
                dinv[i] = rsqrtf((float)(ub - lo + 1));
            }
        }
    }
}

// W[K][N] fp32 -> Wt[NP][K] fp16, zero-padded for c in [N, NP). K pow2.
__global__ __launch_bounds__(256) void k_wcast(const float* __restrict__ W,
                                               _Float16* __restrict__ Wt,
                                               int N, int K, int kbits, int total) {
    int i = blockIdx.x * 256 + threadIdx.x;
    if (i < total) {
        int c = i >> kbits;
        int k = i & (K - 1);
        Wt[i] = (c < N) ? (_Float16)W[(size_t)k * N + c] : (_Float16)0.f;
    }
}

// ---------------------------- MFMA GEMM (B-resident) -----------------------
// C[M,N] = A[M,K] @ W[K,N] via v_mfma_f32_16x16x32_f16.
// Whole Wt [BN][K] fp16 staged once into LDS (stride K+8 halfs: 16B-aligned
// rows, uniform bank spread for b128 frag reads). k-loop has NO barriers:
// A fragments load global->register directly (rows contiguous); waves are
// fully independent. MT row-tiles per wave amortize the LDS B reads.

template <int K, int BN, int MT, typename AT, typename OT>
__global__ __launch_bounds__(256) void gemm_bres(const AT* __restrict__ A,
                                                 const _Float16* __restrict__ Wt,
                                                 const float* __restrict__ bias,
                                                 OT* __restrict__ C,
                                                 int M, int N) {
    constexpr int KP = K + 8;
    constexpr int NT = BN / 16;
    __shared__ __align__(16) _Float16 Bs[BN * KP];

    const int tid  = threadIdx.x;
    const int lane = tid & 63;
    const int wv   = tid >> 6;
    const int qd   = lane >> 4;
    const int ln15 = lane & 15;
    const int bm   = blockIdx.x * (64 * MT);

    // stage all of Wt into LDS (once)
    constexpr int TOT = BN * K / 8;
    for (int i = tid; i < TOT; i += 256) {
        int idx = i * 8;
        int col = idx / K;
        int kk  = idx % K;
        *(uint4*)&Bs[col * KP + kk] = *(const uint4*)(Wt + idx);
    }
    __syncthreads();

    floatx4 acc[MT][NT];
    #pragma unroll
    for (int mt = 0; mt < MT; ++mt)
        #pragma unroll
        for (int c = 0; c < NT; ++c) acc[mt][c] = (floatx4){0.f, 0.f, 0.f, 0.f};

    int rw[MT];
    #pragma unroll
    for (int mt = 0; mt < MT; ++mt) {
        int r = bm + (wv * MT + mt) * 16 + ln15;
        rw[mt] = (r < M) ? r : (M - 1);   // clamp: loads safe, stores guarded
    }

    #pragma unroll
    for (int ks = 0; ks < K / 32; ++ks) {
        half8 a[MT];
        #pragma unroll
        for (int mt = 0; mt < MT; ++mt) {
            if constexpr (std::is_same<AT, float>::value) {
                const float* p = A + (size_t)rw[mt] * K + ks * 32 + qd * 8;
                float4 v0 = *(const float4*)p;
                float4 v1 = *(const float4*)(p + 4);
                half8 h;
                h[0] = (_Float16)v0.x; h[1] = (_Float16)v0.y;
                h[2] = (_Float16)v0.z; h[3] = (_Float16)v0.w;
                h[4] = (_Float16)v1.x; h[5] = (_Float16)v1.y;
                h[6] = (_Float16)v1.z; h[7] = (_Float16)v1.w;
                a[mt] = h;
            } else {
                a[mt] = *(const half8*)((const _Float16*)A +
                                        (size_t)rw[mt] * K + ks * 32 + qd * 8);
            }
        }
        #pragma unroll
        for (int c = 0; c < NT; ++c) {
            half8 b = *(const half8*)&Bs[(c * 16 + ln15) * KP + ks * 32 + qd * 8];
            #pragma unroll
            for (int mt = 0; mt < MT; ++mt)
                acc[mt][c] = __builtin_amdgcn_mfma_f32_16x16x32_f16(a[mt], b,
                                                                    acc[mt][c], 0, 0, 0);
        }
    }

    #pragma unroll
    for (int mt = 0; mt < MT; ++mt) {
        int baseRow = bm + (wv * MT + mt) * 16 + qd * 4;
        #pragma unroll
        for (int c = 0; c < NT; ++c) {
            int col = c * 16 + ln15;
            if constexpr (std::is_same<OT, _Float16>::value) {
                #pragma unroll
                for (int r = 0; r < 4; ++r) {
                    int row = baseRow + r;
                    if (row < M) C[(size_t)row * N + col] = (_Float16)acc[mt][c][r];
                }
            } else {
                float bv = (col < N && bias) ? bias[col] : 0.f;
                #pragma unroll
                for (int r = 0; r < 4; ++r) {
                    int row = baseRow + r;
                    if (row < M && col < N)
                        ((float*)C)[(size_t)row * N + col] = acc[mt][c][r] + bv;
                }
            }
        }
    }
}

// ---------------------------- aggregation ----------------------------------
// One wave per node; 4 groups x 16 lanes, group owns one edge per step,
// lane loads dwordx4 (8 fp16 cols). R8: explicit 16-edge batches -- 8
// ds_bpermute then 4 independent dwordx4 gathers issued back-to-back
// (4KB in flight per wave) before the FMA chain.

__global__ __launch_bounds__(256) void gcn_agg(const unsigned int* __restrict__ h,
                                               const int* __restrict__ rowptr,
                                               const int* __restrict__ srcS,
                                               const float* __restrict__ dinv,
                                               const float* __restrict__ bias,
                                               unsigned int* __restrict__ out,
                                               int n, int do_relu) {
    int node = blockIdx.x * 4 + (threadIdx.x >> 6);
    if (node >= n) return;
    const int lane = threadIdx.x & 63;
    const int g    = lane >> 4;      // edge group 0..3
    const int t    = lane & 15;      // col chunk: cols [t*8, t*8+8)

    const _Float16* hb = (const _Float16*)h;

    float di = dinv[node];
    int e0 = rowptr[node];
    int e1 = rowptr[node + 1];

    half8 sv = *(const half8*)(hb + (size_t)(unsigned)node * 128 + t * 8);
    const float4* b4 = (const float4*)bias;
    float4 blo = b4[t * 2 + 0];
    float4 bhi = b4[t * 2 + 1];

    float acc[8];
    #pragma unroll
    for (int i = 0; i < 8; ++i) acc[i] = 0.f;

    for (int ce = e0; ce < e1; ce += 64) {
        int cnt = e1 - ce;
        cnt = (cnt < 64) ? cnt : 64;
        int colv = 0, wval = 0;
        if (lane < cnt) {
            int c = srcS[ce + lane];
            colv = c;
            wval = __float_as_int(di * dinv[c]);
        }
        int d = 0;
        // 16 edges per batch: 8 bpermutes, then 4 independent 1KB gathers.
        for (; d + 16 <= cnt; d += 16) {
            int i0 = (d + 0 + g) << 2;
            int i1 = (d + 4 + g) << 2;
            int i2 = (d + 8 + g) << 2;
            int i3 = (d + 12 + g) << 2;
            int c0 = __builtin_amdgcn_ds_bpermute(i0, colv);
            int c1 = __builtin_amdgcn_ds_bpermute(i1, colv);
            int c2 = __builtin_amdgcn_ds_bpermute(i2, colv);
            int c3 = __builtin_amdgcn_ds_bpermute(i3, colv);
            int w0i = __builtin_amdgcn_ds_bpermute(i0, wval);
            int w1i = __builtin_amdgcn_ds_bpermute(i1, wval);
            int w2i = __builtin_amdgcn_ds_bpermute(i2, wval);
            int w3i = __builtin_amdgcn_ds_bpermute(i3, wval);
            half8 h0 = *(const half8*)(hb + (size_t)(unsigned)c0 * 128 + t * 8);
            half8 h1 = *(const half8*)(hb + (size_t)(unsigned)c1 * 128 + t * 8);
            half8 h2 = *(const half8*)(hb + (size_t)(unsigned)c2 * 128 + t * 8);
            half8 h3 = *(const half8*)(hb + (size_t)(unsigned)c3 * 128 + t * 8);
            float w0 = __int_as_float(w0i);
            float w1 = __int_as_float(w1i);
            float w2 = __int_as_float(w2i);
            float w3 = __int_as_float(w3i);
            #pragma unroll
            for (int i = 0; i < 8; ++i) acc[i] += (float)h0[i] * w0;
            #pragma unroll
            for (int i = 0; i < 8; ++i) acc[i] += (float)h1[i] * w1;
            #pragma unroll
            for (int i = 0; i < 8; ++i) acc[i] += (float)h2[i] * w2;
            #pragma unroll
            for (int i = 0; i < 8; ++i) acc[i] += (float)h3[i] * w3;
        }
        // remainder (tail groups read zeroed slots -> w=0, harmless)
        for (; d < cnt; d += 4) {
            int idx = (d + g) << 2;
            int c   = __builtin_amdgcn_ds_bpermute(idx, colv);
            float w = __int_as_float(__builtin_amdgcn_ds_bpermute(idx, wval));
            half8 hv = *(const half8*)(hb + (size_t)(unsigned)c * 128 + t * 8);
            #pragma unroll
            for (int i = 0; i < 8; ++i)
                acc[i] += (float)hv[i] * w;
        }
    }

    #pragma unroll
    for (int i = 0; i < 8; ++i) acc[i] += __shfl_xor(acc[i], 16);
    #pragma unroll
    for (int i = 0; i < 8; ++i) acc[i] += __shfl_xor(acc[i], 32);

    float s = di * di;
    float bb[8] = {blo.x, blo.y, blo.z, blo.w, bhi.x, bhi.y, bhi.z, bhi.w};
    half8 o;
    #pragma unroll
    for (int i = 0; i < 8; ++i) {
        float v = acc[i] + (float)sv[i] * s + bb[i];
        if (do_relu) v = fmaxf(v, 0.f);
        o[i] = (_Float16)v;
    }
    if (g == 0)
        *(half8*)((_Float16*)out + (size_t)(unsigned)node * 128 + t * 8) = o;
}

// ------------------------------- launch ------------------------------------

extern "C" void kernel_launch(void* const* d_in, const int* in_sizes, int n_in,
                              void* d_out, int out_size, void* d_ws, size_t ws_size,
                              hipStream_t stream) {
    const float* x  = (const float*)d_in[0];
    const int* eidx = (const int*)d_in[1];
    const float* W1 = (const float*)d_in[2];
    const float* b1 = (const float*)d_in[3];
    const float* W2 = (const float*)d_in[4];
    const float* b2 = (const float*)d_in[5];
    const float* Wc = (const float*)d_in[6];
    const float* bc = (const float*)d_in[7];
    float* out = (float*)d_out;

    const int NF = 256, NH = 128, NC = 40;
    const int n = in_sizes[0] / NF;    // 100000
    const int E = in_sizes[1] / 2;     // 1600000
    const int* src = eidx;
    const int* dst = eidx + E;

    const int nblk = (E + EPB - 1) / EPB;          // 196
    const int hm   = 512 * nblk;                   // 100352
    const int nbA  = (hm + 4095) / 4096;           // 25

    char* wsb = (char*)d_ws;
    size_t off = 0;
    auto alloc = [&](size_t bytes) {
        char* p = wsb + off;
        off = (off + bytes + 511) & ~(size_t)511;
        return p;
    };
    _Float16* hbuf = (_Float16*)alloc((size_t)n * NH * 2);  // 25.6 MB
    _Float16* abuf = (_Float16*)alloc((size_t)n * NH * 2);  // 25.6 MB
    _Float16* W1t  = (_Float16*)alloc((size_t)128 * 256 * 2);
    _Float16* W2t  = (_Float16*)alloc((size_t)128 * 128 * 2);
    _Float16* Wct  = (_Float16*)alloc((size_t)48 * 128 * 2);
    unsigned long long* eB = (unsigned long long*)alloc((size_t)E * 8);  // 12.8 MB
    int* srcS      = (int*)alloc((size_t)E * 4);            // 6.4 MB
    int* histM     = (int*)alloc((size_t)hm * 4);
    int* histS     = (int*)alloc((size_t)hm * 4);
    int* rowptr    = (int*)alloc((size_t)(n + 1) * 4);
    float* dinv    = (float*)alloc((size_t)n * 4);
    int* bsumA     = (int*)alloc(1024);

    // ---- CSR build: 2-level bucket sort, no global atomics ----
    k_histA<<<nblk, 256, 0, stream>>>(dst, histM, E, nblk);
    k_scan1<16><<<nbA, 256, 0, stream>>>(histM, bsumA, hm);
    k_scan2<<<1, 256, 0, stream>>>(bsumA, nbA);
    k_scan3<16><<<nbA, 256, 0, stream>>>(histM, bsumA, histS, hm);
    k_scatterA<<<nblk, 256, 0, stream>>>(src, dst, histS, eB, E, nblk);
    k_sortB<<<512, 256, 0, stream>>>(eB, histS, srcS, rowptr, dinv, n, E, nblk);

    // ---- weights ----
    k_wcast<<<(128 * 256 + 255) / 256, 256, 0, stream>>>(W1, W1t, 128, 256, 8, 128 * 256);
    k_wcast<<<(128 * 128 + 255) / 256, 256, 0, stream>>>(W2, W2t, 128, 128, 7, 128 * 128);
    k_wcast<<<(48 * 128 + 255) / 256, 256, 0, stream>>>(Wc, Wct, 40, 128, 7, 48 * 128);

    // ---- layers ----
    const int gB = (n + 127) / 128;   // 782 blocks, 128 rows each (MT=2)
    gemm_bres<256, 128, 2, float, _Float16><<<gB, 256, 0, stream>>>(x, W1t, nullptr, hbuf, n, NH);
    gcn_agg<<<(n + 3) / 4, 256, 0, stream>>>((const unsigned int*)hbuf, rowptr, srcS, dinv, b1,
                                             (unsigned int*)abuf, n, 1);
    gemm_bres<128, 128, 2, _Float16, _Float16><<<gB, 256, 0, stream>>>(abuf, W2t, nullptr, hbuf, n, NH);
    gcn_agg<<<(n + 3) / 4, 256, 0, stream>>>((const unsigned int*)hbuf, rowptr, srcS, dinv, b2,
                                             (unsigned int*)abuf, n, 1);
    gemm_bres<128, 48, 2, _Float16, float><<<gB, 256, 0, stream>>>(abuf, Wct, bc, out, n, NC);
}